// Round 1
// baseline (222.168 us; speedup 1.0000x reference)
//
#include <hip/hip_runtime.h>
#include <stdint.h>

using f32x4 = __attribute__((ext_vector_type(4))) float;
using s16x8 = __attribute__((ext_vector_type(8))) short;
using u16x4 = __attribute__((ext_vector_type(4))) unsigned short;

__device__ __forceinline__ unsigned short f2bf(float f){
  union { float f; unsigned u; } x; x.f = f;
  return (unsigned short)((x.u + 0x7FFFu + ((x.u >> 16) & 1u)) >> 16);
}

#define MFMA(A,B,C) __builtin_amdgcn_mfma_f32_16x16x32_bf16((A),(B),(C),0,0,0)

constexpr int   L     = 2048;
constexpr int   HE    = 1024;     // H*E floats per (b,l) row
constexpr float SCALE = 0.125f;   // 1/sqrt(64)

// Block: 512 threads = 8 waves. Each block: one (b,h) and 128 query rows.
// Each wave owns 16 query rows. Key tiles of 64, staged in LDS as bf16.
__global__ __launch_bounds__(512)
void attn_band(const float* __restrict__ Qg, const float* __restrict__ Kg,
               const float* __restrict__ Vg, float* __restrict__ Og)
{
  __shared__ __align__(16) unsigned short Ks[64*64];     // [key][e]  swizzled
  __shared__ __align__(16) unsigned short Vs[64*64];     // [e][key]  swizzled (transposed)
  __shared__ __align__(16) unsigned short Ps[8][16*64];  // per-wave P [q][key] swizzled

  const int tid  = threadIdx.x;
  const int wave = tid >> 6;
  const int lane = tid & 63;
  const int lo16 = lane & 15;
  const int hi4  = lane >> 4;

  const int gid = blockIdx.x;
  const int qb  = gid & 15;          // 16 q-blocks of 128 rows
  const int bh  = gid >> 4;          // 64 (b,h) pairs
  const int b   = bh >> 4;
  const int h   = bh & 15;
  const int off = (1 << (h >> 2)) - 1;

  const int    r0   = qb * 128;
  const size_t base = (size_t)b * L * HE + (size_t)h * 64;

  // ---- Q fragments: wave's 16 rows, E=64 in two K=32 chunks ----
  const int qrow0 = r0 + wave * 16;
  s16x8 qf[2];
  {
    const float* qp = Qg + base + (size_t)(qrow0 + lo16) * HE;
    #pragma unroll
    for (int ec = 0; ec < 2; ++ec){
      const int e0 = ec*32 + hi4*8;
      s16x8 v;
      #pragma unroll
      for (int j = 0; j < 8; ++j) v[j] = (short)f2bf(qp[e0 + j]);
      qf[ec] = v;
    }
  }

  f32x4 acc[4];
  #pragma unroll
  for (int et = 0; et < 4; ++et) acc[et] = f32x4{0.f,0.f,0.f,0.f};
  float m_run[4], l_run[4];
  #pragma unroll
  for (int i = 0; i < 4; ++i){ m_run[i] = -1e30f; l_run[i] = 0.f; }

  const int j0 = (r0 + off + 1) >> 6;   // first key tile with any live entry

  for (int jt = j0; jt < 32; ++jt){
    const int s0 = jt * 64;
    __syncthreads();                    // previous tile's LDS reads done

    // ---- stage K tile: Ks[key][e], bf16, XOR-swizzled ----
    {
      const int f4    = tid & 15;       // float4 column
      const int rbase = tid >> 4;       // 0..31
      #pragma unroll
      for (int p = 0; p < 2; ++p){
        const int row = p*32 + rbase;
        const float4 vv = *reinterpret_cast<const float4*>(
            Kg + base + (size_t)(s0 + row) * HE + f4*4);
        u16x4 w; w[0]=f2bf(vv.x); w[1]=f2bf(vv.y); w[2]=f2bf(vv.z); w[3]=f2bf(vv.w);
        const int idx = row*64 + ((f4*4) ^ ((row & 7) << 3));
        *reinterpret_cast<u16x4*>(&Ks[idx]) = w;
      }
    }
    // ---- stage V tile transposed: Vs[e][key], bf16, XOR-swizzled ----
    {
      const int kb = tid >> 5;          // 0..15 -> keys 4kb..4kb+3
      const int e0 = (tid & 31) * 2;    // two e per thread
      float2 c[4];
      #pragma unroll
      for (int j = 0; j < 4; ++j)
        c[j] = *reinterpret_cast<const float2*>(
            Vg + base + (size_t)(s0 + 4*kb + j) * HE + e0);
      #pragma unroll
      for (int i = 0; i < 2; ++i){
        const int e = e0 + i;
        u16x4 w;
        w[0] = f2bf(i ? c[0].y : c[0].x);
        w[1] = f2bf(i ? c[1].y : c[1].x);
        w[2] = f2bf(i ? c[2].y : c[2].x);
        w[3] = f2bf(i ? c[3].y : c[3].x);
        const int idx = e*64 + ((kb*4) ^ ((e & 7) << 3));
        *reinterpret_cast<u16x4*>(&Vs[idx]) = w;
      }
    }
    __syncthreads();

    // wave-level skip: tile entirely masked for this wave's rows (never tile 31)
    if (jt < 31 && s0 + 63 <= qrow0 + off) continue;

    // ---- S = Q K^T : 4 key sub-tiles of 16, each 2 MFMAs over E ----
    f32x4 S[4];
    #pragma unroll
    for (int kt = 0; kt < 4; ++kt){
      const int key = kt*16 + lo16;
      f32x4 z = {0.f,0.f,0.f,0.f};
      #pragma unroll
      for (int ec = 0; ec < 2; ++ec){
        const int e = ec*32 + hi4*8;
        const s16x8 kf = *reinterpret_cast<const s16x8*>(
            &Ks[key*64 + (e ^ ((key & 7) << 3))]);
        z = MFMA(qf[ec], kf, z);
      }
      S[kt] = z;
    }

    // ---- mask + scale (C-layout: row = 4*hi4+i, col = lo16) ----
    #pragma unroll
    for (int kt = 0; kt < 4; ++kt){
      const int kg = s0 + kt*16 + lo16;
      #pragma unroll
      for (int i = 0; i < 4; ++i){
        const int qg = qrow0 + hi4*4 + i;
        const bool ok = (kg > qg + off) || (kg == L-1);
        S[kt][i] = ok ? S[kt][i]*SCALE : -1e30f;
      }
    }

    // ---- online softmax: row max across 64 keys (in-lane + 16-lane butterfly) ----
    #pragma unroll
    for (int i = 0; i < 4; ++i){
      float t = fmaxf(fmaxf(S[0][i],S[1][i]), fmaxf(S[2][i],S[3][i]));
      t = fmaxf(t, __shfl_xor(t,1));
      t = fmaxf(t, __shfl_xor(t,2));
      t = fmaxf(t, __shfl_xor(t,4));
      t = fmaxf(t, __shfl_xor(t,8));
      const float mn = fmaxf(m_run[i], t);
      const float rs = __expf(m_run[i] - mn);
      m_run[i]  = mn;
      l_run[i] *= rs;
      acc[0][i] *= rs; acc[1][i] *= rs; acc[2][i] *= rs; acc[3][i] *= rs;
    }

    // ---- P = exp(S - m), row-sum, write to per-wave LDS for relayout ----
    unsigned short* pw = Ps[wave];
    float rsum[4] = {0.f,0.f,0.f,0.f};
    #pragma unroll
    for (int kt = 0; kt < 4; ++kt){
      #pragma unroll
      for (int i = 0; i < 4; ++i){
        const float p = __expf(S[kt][i] - m_run[i]);
        rsum[i] += p;
        const int qr  = hi4*4 + i;
        const int col = kt*16 + lo16;
        pw[qr*64 + (col ^ ((qr & 7) << 3))] = f2bf(p);
      }
    }
    #pragma unroll
    for (int i = 0; i < 4; ++i){
      float t = rsum[i];
      t += __shfl_xor(t,1); t += __shfl_xor(t,2);
      t += __shfl_xor(t,4); t += __shfl_xor(t,8);
      l_run[i] += t;
    }

    // ---- O += P V : A-frag from Ps, B-frag from Vs ----
    #pragma unroll
    for (int kc = 0; kc < 2; ++kc){
      const int kk = kc*32 + hi4*8;
      const s16x8 pf = *reinterpret_cast<const s16x8*>(
          &pw[lo16*64 + (kk ^ ((lo16 & 7) << 3))]);
      #pragma unroll
      for (int et = 0; et < 4; ++et){
        const int e = et*16 + lo16;
        const s16x8 vf = *reinterpret_cast<const s16x8*>(
            &Vs[e*64 + (kk ^ ((e & 7) << 3))]);
        acc[et] = MFMA(pf, vf, acc[et]);
      }
    }
  }

  // ---- epilogue: O = acc / l ----
  #pragma unroll
  for (int i = 0; i < 4; ++i){
    const float inv = 1.0f / l_run[i];
    const int   qg  = qrow0 + hi4*4 + i;
    float* op = Og + base + (size_t)qg * HE;
    #pragma unroll
    for (int et = 0; et < 4; ++et)
      op[et*16 + lo16] = acc[et][i] * inv;
  }
}

extern "C" void kernel_launch(void* const* d_in, const int* in_sizes, int n_in,
                              void* d_out, int out_size, void* d_ws, size_t ws_size,
                              hipStream_t stream) {
  const float* Q = (const float*)d_in[0];
  const float* K = (const float*)d_in[1];
  const float* V = (const float*)d_in[2];
  float* O = (float*)d_out;
  // grid: 16 q-blocks * 4 B * 16 H = 1024 blocks
  attn_band<<<dim3(1024), dim3(512), 0, stream>>>(Q, K, V, O);
}